// Round 7
// baseline (236.617 us; speedup 1.0000x reference)
//
#include <hip/hip_runtime.h>

// EAConv: EM-routing neighbor aggregation + temporal blend, fully fused.
// T=3, b=1, n=50000, d=64, m=16, K=4, dd=16.
// R13: LDS-pipe attack. Cycle model validated on R10/R11/R12:
//   time = max(LDS_CU, VALU_CU/4). R11: LDS 84xb128+63xb32 = 1373 cy/wave
//   x195 waves/CU = 112us == measured 114us (LDS-bound); VALU 56us -> 49%
//   busy == measured. LDS ops are ~24x costlier per-CU than VALU ops here.
// Row-form layout: lane (k,p) holds zh[16]=zhat[p][16k..+15] and computes
// the FULL u row slice redundantly: ur[j] = xh[j] + rowsum16(wf*zh[j]).
//   - u/w/rz row all-gathers via LDS: GONE (were 5x53.8 cy/t)
//   - z column reads: GONE (were 16xb32 = 92.8 cy/t)
//   - per-factor norms/dots: per-lane serial FMA (normalize is over dd=16)
//   - gather: shfl-free -- lane loads ITS OWN neighbor row j_p as 4x16B
//     (instr c covers 64B chunk c of 16 rows: same 16-line coalescing,
//     zero ds_bpermute); LDS only for the 4-write+4-read transpose.
//   - zh pre-scaled by rz (0 if invalid): invalid neighbors contribute 0
//     to updates AND get logit=0 -> e=1, matching the reference pad row.
// Remaining LDS/t: 8 b128 + softmax shuffles ~= 120 cy -> ~24us/CU.
// VALU/t ~= 460 ops -> ~58us/CU/4. Now VALU-bound.

constexpr int T = 3;
constexpr int N = 50000;
constexpr int D = 64;
constexpr int M = 16;
constexpr float EPS2 = 1e-24f;  // (1e-12)^2

template <int CTRL>
__device__ __forceinline__ float dpp_add(float v) {
    // mov_dpp with undef old -> GCNDPPCombine fuses into v_add_f32_dpp
    int rot = __builtin_amdgcn_mov_dpp(__float_as_int(v), CTRL, 0xF, 0xF, false);
    return v + __int_as_float(rot);
}
// sum over the 16 lanes of a DPP row; result broadcast within the row
__device__ __forceinline__ float rowsum16(float v) {
    v = dpp_add<0x128>(v);  // row_ror:8
    v = dpp_add<0x124>(v);  // row_ror:4
    v = dpp_add<0x122>(v);  // row_ror:2
    v = dpp_add<0x121>(v);  // row_ror:1
    return v;
}

__global__ __launch_bounds__(256, 4) void eaconv_fused(
    const float* __restrict__ x_all,   // [T,N,D]
    const int*   __restrict__ nbr_all, // [T,N,M]
    float*       __restrict__ out)     // [T,N,D]
{
    __shared__ float zs[4][M * 64];    // 4KB/wave transpose buffer (swizzled)
    const int wv   = threadIdx.x >> 6;
    const int i    = blockIdx.x * 4 + wv;   // N%4==0: no guard needed
    const int lane = threadIdx.x & 63;
    const int p  = lane & 15;          // neighbor index owned by this lane
    const int k  = lane >> 4;          // factor
    const int x7 = p & 7;
    char* zsb = (char*)zs[wv];

    // t-invariant LDS byte addresses. Slot of granule g in row p:
    // 256*p + 16*(g ^ x7). Write instr c deposits granule g=4c|k of row p;
    // read q fetches granule g=4k|q (lane's own row slice [16k..16k+15]).
    // Per-16-lane phase both patterns are 2-way (free, m136).
    const int wa0 = 256 * p + (((k     ) ^ x7) << 4);
    const int wa1 = 256 * p + (((k |  4) ^ x7) << 4);
    const int wa2 = 256 * p + (((k |  8) ^ x7) << 4);
    const int wa3 = 256 * p + (((k | 12) ^ x7) << 4);
    const int c4  = (4 * k) ^ x7;
    const int ra0 = 256 * p + ((c4 ^ 0) << 4);
    const int ra1 = 256 * p + ((c4 ^ 1) << 4);
    const int ra2 = 256 * p + ((c4 ^ 2) << 4);
    const int ra3 = 256 * p + ((c4 ^ 3) << 4);

    float accr[16];                    // temporal-blend carry (row form)
    const float s1q = 0.25f * 0.7310585786300049f;  // 0.25*sigmoid(1)

#pragma unroll
    for (int t = 0; t < T; ++t) {
        const float* x = x_all + (size_t)t * N * D;
        int j = nbr_all[((size_t)t * N + i) * M + p];
        const bool valid = (unsigned)j < (unsigned)N;
        j = valid ? j : 0;

        // ---- shfl-free coalesced gather: own row j_p, 4x16B.
        // instr c: dims [16c+4k .. +3]; wave touches 16 rows x 64B chunk c.
        const float* zbase = x + (size_t)j * D + 4 * k;
        const float4 g0 = *(const float4*)(zbase +  0);
        const float4 g1 = *(const float4*)(zbase + 16);
        const float4 g2 = *(const float4*)(zbase + 32);
        const float4 g3 = *(const float4*)(zbase + 48);

        // own-x row slice (broadcast within each 16-lane row; L1-friendly)
        const float4* xr4 = (const float4*)(x + (size_t)i * D + 16 * k);
        const float4 h0 = xr4[0], h1 = xr4[1], h2 = xr4[2], h3 = xr4[3];

        // ---- LDS transpose: write granules (4c|k) of row p ----
        *(float4*)(zsb + wa0) = g0;
        *(float4*)(zsb + wa1) = g1;
        *(float4*)(zsb + wa2) = g2;
        *(float4*)(zsb + wa3) = g3;

        // ---- own factor row, normalized (serial, no cross-lane) ----
        float xh[16] = {h0.x,h0.y,h0.z,h0.w, h1.x,h1.y,h1.z,h1.w,
                        h2.x,h2.y,h2.z,h2.w, h3.x,h3.y,h3.z,h3.w};
        float a0 = xh[0]*xh[0], a1 = xh[1]*xh[1],
              a2 = xh[2]*xh[2], a3 = xh[3]*xh[3];
#pragma unroll
        for (int q = 4; q < 16; q += 4) {
            a0 = fmaf(xh[q+0], xh[q+0], a0);
            a1 = fmaf(xh[q+1], xh[q+1], a1);
            a2 = fmaf(xh[q+2], xh[q+2], a2);
            a3 = fmaf(xh[q+3], xh[q+3], a3);
        }
        const float rx = __builtin_amdgcn_rsqf(fmaxf((a0+a1)+(a2+a3), EPS2));
#pragma unroll
        for (int q = 0; q < 16; ++q) xh[q] *= rx;

        // ---- neighbor row slice zh = z[p][16k..16k+15], then zhat ----
        const float4 z0 = *(const float4*)(zsb + ra0);
        const float4 z1 = *(const float4*)(zsb + ra1);
        const float4 z2 = *(const float4*)(zsb + ra2);
        const float4 z3 = *(const float4*)(zsb + ra3);
        float zh[16] = {z0.x,z0.y,z0.z,z0.w, z1.x,z1.y,z1.z,z1.w,
                        z2.x,z2.y,z2.z,z2.w, z3.x,z3.y,z3.z,z3.w};
        float b0 = zh[0]*zh[0], b1 = zh[1]*zh[1],
              b2 = zh[2]*zh[2], b3 = zh[3]*zh[3];
#pragma unroll
        for (int q = 4; q < 16; q += 4) {
            b0 = fmaf(zh[q+0], zh[q+0], b0);
            b1 = fmaf(zh[q+1], zh[q+1], b1);
            b2 = fmaf(zh[q+2], zh[q+2], b2);
            b3 = fmaf(zh[q+3], zh[q+3], b3);
        }
        float rz = __builtin_amdgcn_rsqf(fmaxf((b0+b1)+(b2+b3), EPS2));
        if (!valid) rz = 0.f;              // invalid -> zh = 0 (pad row)
#pragma unroll
        for (int q = 0; q < 16; ++q) zh[q] *= rz;

        // ---- iter 0: dir(u0) = rowsum_p(zh) + 4*xh (1/4 folded out) ----
        float ur[16];
#pragma unroll
        for (int q = 0; q < 16; ++q)
            ur[q] = fmaf(xh[q], 4.0f, rowsum16(zh[q]));
        float n0 = ur[0]*ur[0], n1 = ur[1]*ur[1],
              n2 = ur[2]*ur[2], n3 = ur[3]*ur[3];
#pragma unroll
        for (int q = 4; q < 16; q += 4) {
            n0 = fmaf(ur[q+0], ur[q+0], n0);
            n1 = fmaf(ur[q+1], ur[q+1], n1);
            n2 = fmaf(ur[q+2], ur[q+2], n2);
            n3 = fmaf(ur[q+3], ur[q+3], n3);
        }
        float inv = __builtin_amdgcn_rsqf(fmaxf((n0+n1)+(n2+n3), EPS2));

        // ---- iters 1..2 (all per-lane / DPP; zero LDS) ----
#pragma unroll
        for (int it = 1; it < 3; ++it) {
            float d0 = zh[0]*ur[0], d1 = zh[1]*ur[1],
                  d2 = zh[2]*ur[2], d3 = zh[3]*ur[3];
#pragma unroll
            for (int q = 4; q < 16; q += 4) {
                d0 = fmaf(zh[q+0], ur[q+0], d0);
                d1 = fmaf(zh[q+1], ur[q+1], d1);
                d2 = fmaf(zh[q+2], ur[q+2], d2);
                d3 = fmaf(zh[q+3], ur[q+3], d3);
            }
            const float logit = ((d0+d1)+(d2+d3)) * inv;  // zhat.uhat
            const float e = __expf(logit);
            float es = e + __shfl_xor(e, 16, 64);         // softmax over k
            es += __shfl_xor(es, 32, 64);
            const float wf = e * __builtin_amdgcn_rcpf(es);
#pragma unroll
            for (int q = 0; q < 16; ++q)
                ur[q] = xh[q] + rowsum16(zh[q] * wf);
            if (it < 2) {
                float m0 = ur[0]*ur[0], m1 = ur[1]*ur[1],
                      m2 = ur[2]*ur[2], m3 = ur[3]*ur[3];
#pragma unroll
                for (int q = 4; q < 16; q += 4) {
                    m0 = fmaf(ur[q+0], ur[q+0], m0);
                    m1 = fmaf(ur[q+1], ur[q+1], m1);
                    m2 = fmaf(ur[q+2], ur[q+2], m2);
                    m3 = fmaf(ur[q+3], ur[q+3], m3);
                }
                inv = __builtin_amdgcn_rsqf(fmaxf((m0+m1)+(m2+m3), EPS2));
            }
        }

        // ---- temporal blend (row form) + store (lanes p=0..3/row) ----
        float wout[16];
        if (t == 0) {
#pragma unroll
            for (int q = 0; q < 16; ++q) { wout[q] = ur[q]; accr[q] = ur[q]; }
        } else if (t == 1) {
#pragma unroll
            for (int q = 0; q < 16; ++q) {
                wout[q] = 0.25f * accr[q] + 0.5f * ur[q];       // e1
                accr[q] = fmaf(s1q, wout[q], 0.125f * accr[q]); // carry
            }
        } else {
#pragma unroll
            for (int q = 0; q < 16; ++q) wout[q] = accr[q] + 0.5f * ur[q];
        }
        float* o = out + ((size_t)t * N + i) * D + 16 * k;
        if (p == 0) ((float4*)o)[0] = make_float4(wout[0],  wout[1],  wout[2],  wout[3]);
        if (p == 1) ((float4*)o)[1] = make_float4(wout[4],  wout[5],  wout[6],  wout[7]);
        if (p == 2) ((float4*)o)[2] = make_float4(wout[8],  wout[9],  wout[10], wout[11]);
        if (p == 3) ((float4*)o)[3] = make_float4(wout[12], wout[13], wout[14], wout[15]);
    }
}

extern "C" void kernel_launch(void* const* d_in, const int* in_sizes, int n_in,
                              void* d_out, int out_size, void* d_ws, size_t ws_size,
                              hipStream_t stream) {
    const float* x_all = (const float*)d_in[0];
    const int*   nbrs  = (const int*)d_in[1];
    float*       out   = (float*)d_out;

    // one wave per node, 4 waves per block, N%4==0
    eaconv_fused<<<N / 4, 256, 0, stream>>>(x_all, nbrs, out);
}

// Round 8
// 188.826 us; speedup vs baseline: 1.2531x; 1.2531x over previous
//
#include <hip/hip_runtime.h>

// EAConv: EM-routing neighbor aggregation + temporal blend, fully fused.
// T=3, b=1, n=50000, d=64, m=16, K=4, dd=16.
// R14 = R11's layout (best: 114us) with the LDS transpose ELIMINATED.
// Cycle model (validated R10-R13): time = max(LDS_CU, VALU_CU/4); LDS ops
// are ~24x per-CU cost of VALU; DPP rowsums ~3x serial FMA (R13 lesson).
// R11 was LDS-bound: 481 LDS-cy/node-t (transpose 48w+48r, zr 16xb32=92.8,
// rz/u/w broadcasts 53.8 each, softmax 23).
// R14 changes:
//  - zr COLUMN form gathered DIRECTLY from global, coalesced: j_m broadcast
//    to SGPR via v_readlane (scalar pipe, free), then zr[m]=x[j_m*D+lane]
//    = one 256B-coalesced global_load_dword per m (16 instrs, 4KB = exactly
//    the z block, L1/L2-hot). Zero LDS.
//  - zrow ROW form loaded per-lane as 4xfloat4 from the same lines (L1 2nd
//    pass). Zero LDS.  -> the 4KB transpose buffer + 188.8 LDS-cy/t GONE.
//  - rz folded into BOTH forms (zhat): invalid -> rz=0 kills everything;
//    logit = dot*inv (no rz term); iter0 update = plain sum of zhat cols.
// Remaining LDS/t: rz bcast (53.8) + 2x u bcast + 2x wf bcast + 4 swizzles
// ~= 292 cy -> ~71us/CU; VALU ~= 55-60us/4SIMD. Expect ~75-95us kernel.
// Lane = d = 16k+p dual-domain: column scalars u/xh/acc at dim d;
// row vectors zrow/rz/dot/wf for neighbor p at factor k.

constexpr int T = 3;
constexpr int N = 50000;
constexpr int D = 64;
constexpr int M = 16;
constexpr float EPS2 = 1e-24f;  // (1e-12)^2

template <int CTRL>
__device__ __forceinline__ float dpp_add(float v) {
    // mov_dpp with undef old -> GCNDPPCombine fuses into v_add_f32_dpp
    int rot = __builtin_amdgcn_mov_dpp(__float_as_int(v), CTRL, 0xF, 0xF, false);
    return v + __int_as_float(rot);
}
// sum over the 16 lanes of a DPP row; result broadcast within the row
__device__ __forceinline__ float rowsum16(float v) {
    v = dpp_add<0x128>(v);  // row_ror:8
    v = dpp_add<0x124>(v);  // row_ror:4
    v = dpp_add<0x122>(v);  // row_ror:2
    v = dpp_add<0x121>(v);  // row_ror:1
    return v;
}

__global__ __launch_bounds__(256, 4) void eaconv_fused(
    const float* __restrict__ x_all,   // [T,N,D]
    const int*   __restrict__ nbr_all, // [T,N,M]
    float*       __restrict__ out)     // [T,N,D]
{
    __shared__ float ub[4][D];         // per-wave u broadcast row (256B)
    __shared__ float wb[4][D];         // per-wave rz/wf broadcast row (256B)
    const int wv   = threadIdx.x >> 6;
    const int i    = blockIdx.x * 4 + wv;   // N%4==0
    const int lane = threadIdx.x & 63;
    const int p  = lane & 15;          // neighbor index (row domain)
    const int k  = lane >> 4;          // factor
    float* uw  = ub[wv];
    float* wwp = wb[wv];
    const int rowb = 64 * k;           // byte offset of row k in u/w buffers

    float acc = 0.f;
    const float s1q = 0.25f * 0.7310585786300049f;  // 0.25*sigmoid(1)

#pragma unroll
    for (int t = 0; t < T; ++t) {
        const float* x = x_all + (size_t)t * N * D;
        int j = nbr_all[((size_t)t * N + i) * M + p];
        const bool valid = (unsigned)j < (unsigned)N;
        j = valid ? j : 0;

        // ---- zr column gather: j_m -> SGPR via readlane; each load is a
        //      fully-coalesced 256B row read. 16 instrs = the whole z block.
        float zr[16];
#pragma unroll
        for (int m = 0; m < 16; ++m) {
            const int jm = __builtin_amdgcn_readlane(j, m);  // lane m = (k0,p=m)
            zr[m] = x[(size_t)jm * D + lane];
        }

        // ---- zrow row slice: own neighbor p, factor k (L1-hot 2nd pass) ----
        const float* zrp = x + (size_t)j * D + 16 * k;
        const float4 r0 = *(const float4*)(zrp + 0);
        const float4 r1 = *(const float4*)(zrp + 4);
        const float4 r2 = *(const float4*)(zrp + 8);
        const float4 r3 = *(const float4*)(zrp + 12);
        float zrow[16] = {r0.x,r0.y,r0.z,r0.w, r1.x,r1.y,r1.z,r1.w,
                          r2.x,r2.y,r2.z,r2.w, r3.x,r3.y,r3.z,r3.w};

        // ---- own x dim + factor norm (DPP over the 16-lane row) ----
        const float xv = x[(size_t)i * D + lane];
        const float sx = rowsum16(xv * xv);
        const float xh = xv * __builtin_amdgcn_rsqf(fmaxf(sx, EPS2));

        // ---- neighbor factor norm (per-lane serial) -> zhat row ----
        float b0 = zrow[0]*zrow[0], b1 = zrow[1]*zrow[1],
              b2 = zrow[2]*zrow[2], b3 = zrow[3]*zrow[3];
#pragma unroll
        for (int q = 4; q < 16; q += 4) {
            b0 = fmaf(zrow[q+0], zrow[q+0], b0);
            b1 = fmaf(zrow[q+1], zrow[q+1], b1);
            b2 = fmaf(zrow[q+2], zrow[q+2], b2);
            b3 = fmaf(zrow[q+3], zrow[q+3], b3);
        }
        float rz = __builtin_amdgcn_rsqf(fmaxf((b0+b1)+(b2+b3), EPS2));
        if (!valid) rz = 0.f;            // pad row -> zhat = 0
#pragma unroll
        for (int q = 0; q < 16; ++q) zrow[q] *= rz;

        // ---- broadcast rz row; scale zr columns -> zhat cols ----
        wwp[lane] = rz;                  // byte 4*(16k+p)
        float rzr[16];
        {
            const float4 v0 = *(const float4*)((char*)wwp + rowb);
            const float4 v1 = *(const float4*)((char*)wwp + rowb + 16);
            const float4 v2 = *(const float4*)((char*)wwp + rowb + 32);
            const float4 v3 = *(const float4*)((char*)wwp + rowb + 48);
            rzr[ 0]=v0.x; rzr[ 1]=v0.y; rzr[ 2]=v0.z; rzr[ 3]=v0.w;
            rzr[ 4]=v1.x; rzr[ 5]=v1.y; rzr[ 6]=v1.z; rzr[ 7]=v1.w;
            rzr[ 8]=v2.x; rzr[ 9]=v2.y; rzr[10]=v2.z; rzr[11]=v2.w;
            rzr[12]=v3.x; rzr[13]=v3.y; rzr[14]=v3.z; rzr[15]=v3.w;
        }
#pragma unroll
        for (int m = 0; m < 16; ++m) zr[m] *= rzr[m];

        // ---- iter 0: u_dir = 4*xh + sum_m zhat[m][d]  (tree sum) ----
        float t0a = zr[0]+zr[1], t0b = zr[2]+zr[3], t0c = zr[4]+zr[5],
              t0d = zr[6]+zr[7], t0e = zr[8]+zr[9], t0f = zr[10]+zr[11],
              t0g = zr[12]+zr[13], t0h = zr[14]+zr[15];
        float u = fmaf(xh, 4.0f,
                       ((t0a+t0b)+(t0c+t0d)) + ((t0e+t0f)+(t0g+t0h)));
        float inv = __builtin_amdgcn_rsqf(fmaxf(rowsum16(u * u), EPS2));
        uw[lane] = u;

        // ---- iters 1..2 ----
#pragma unroll
        for (int it = 1; it < 3; ++it) {
            // dot[p,k] = zhat-row . u-row (u broadcast through LDS)
            float urow[16];
            {
                const float4 v0 = *(const float4*)((char*)uw + rowb);
                const float4 v1 = *(const float4*)((char*)uw + rowb + 16);
                const float4 v2 = *(const float4*)((char*)uw + rowb + 32);
                const float4 v3 = *(const float4*)((char*)uw + rowb + 48);
                urow[ 0]=v0.x; urow[ 1]=v0.y; urow[ 2]=v0.z; urow[ 3]=v0.w;
                urow[ 4]=v1.x; urow[ 5]=v1.y; urow[ 6]=v1.z; urow[ 7]=v1.w;
                urow[ 8]=v2.x; urow[ 9]=v2.y; urow[10]=v2.z; urow[11]=v2.w;
                urow[12]=v3.x; urow[13]=v3.y; urow[14]=v3.z; urow[15]=v3.w;
            }
            float d0 = zrow[0]*urow[0], d1 = zrow[1]*urow[1],
                  d2 = zrow[2]*urow[2], d3 = zrow[3]*urow[3];
#pragma unroll
            for (int q = 4; q < 16; q += 4) {
                d0 = fmaf(zrow[q+0], urow[q+0], d0);
                d1 = fmaf(zrow[q+1], urow[q+1], d1);
                d2 = fmaf(zrow[q+2], urow[q+2], d2);
                d3 = fmaf(zrow[q+3], urow[q+3], d3);
            }
            const float logit = ((d0+d1)+(d2+d3)) * inv;  // zhat.uhat
            const float e = __expf(logit);
            float es = e + __shfl_xor(e, 16, 64);         // softmax over k
            es += __shfl_xor(es, 32, 64);
            const float wf = e * __builtin_amdgcn_rcpf(es);

            // broadcast wf row; column update = 16 serial FMA
            wwp[lane] = wf;
            float wfr[16];
            {
                const float4 v0 = *(const float4*)((char*)wwp + rowb);
                const float4 v1 = *(const float4*)((char*)wwp + rowb + 16);
                const float4 v2 = *(const float4*)((char*)wwp + rowb + 32);
                const float4 v3 = *(const float4*)((char*)wwp + rowb + 48);
                wfr[ 0]=v0.x; wfr[ 1]=v0.y; wfr[ 2]=v0.z; wfr[ 3]=v0.w;
                wfr[ 4]=v1.x; wfr[ 5]=v1.y; wfr[ 6]=v1.z; wfr[ 7]=v1.w;
                wfr[ 8]=v2.x; wfr[ 9]=v2.y; wfr[10]=v2.z; wfr[11]=v2.w;
                wfr[12]=v3.x; wfr[13]=v3.y; wfr[14]=v3.z; wfr[15]=v3.w;
            }
            u = xh;
#pragma unroll
            for (int m = 0; m < 16; ++m) u = fmaf(wfr[m], zr[m], u);
            if (it < 2) {
                inv = __builtin_amdgcn_rsqf(fmaxf(rowsum16(u * u), EPS2));
                uw[lane] = u;
            }
        }

        // ---- temporal blend (scalar) + coalesced store ----
        float wout;
        if (t == 0)      { wout = u; acc = u; }
        else if (t == 1) { wout = 0.25f * acc + 0.5f * u;
                           acc = fmaf(s1q, wout, 0.125f * acc); }
        else             { wout = acc + 0.5f * u; }
        out[((size_t)t * N + i) * D + lane] = wout;
    }
}

extern "C" void kernel_launch(void* const* d_in, const int* in_sizes, int n_in,
                              void* d_out, int out_size, void* d_ws, size_t ws_size,
                              hipStream_t stream) {
    const float* x_all = (const float*)d_in[0];
    const int*   nbrs  = (const int*)d_in[1];
    float*       out   = (float*)d_out;

    // one wave per node, 4 waves per block, N%4==0
    eaconv_fused<<<N / 4, 256, 0, stream>>>(x_all, nbrs, out);
}

// Round 9
// 184.737 us; speedup vs baseline: 1.2808x; 1.0221x over previous
//
#include <hip/hip_runtime.h>

// EAConv: EM-routing neighbor aggregation + temporal blend, fully fused.
// T=3, b=1, n=50000, d=64, m=16, K=4, dd=16.
// R15 = R14 + cross-t software pipelining + raw-z weight folding.
// Model (R11/R13/R14): no pipe >55% busy, wall ~= 2x VALU-busy ->
// LATENCY-bound: each t's chain (j load -> readlane -> 16 zr loads ->
// rz bcast -> iter0..2) is fully serial, x3 per wave. The t-slices are
// data-independent, so:
//  - top of t: load j(t+1), x(t+1)
//  - after iter0: readlane j(t+1), issue zr(t+1) x16 + zrow(t+1) x4 into
//    fresh regs; ~1500cy of iters 1-2 compute hides their latency.
//  - t-loop fully unrolled: rotation is free SSA renaming.
// Raw-z folding (from R11): zr/zrow stay RAW. iter0 weight IS rz
// (broadcast like wf); later weights are wf*rz (row domain, rz native);
// logit = dot_raw * (rz*inv). Invalid neighbor -> rz=0 kills everything.
// __launch_bounds__(256,3): ~170-reg budget for the +33-reg prefetch
// window (R10 precedent: no spill at this bound; R8: occupancy-insensitive).
// Lane = d = 16k+p dual-domain: column scalars u/xh/acc at dim d;
// row data zrow/rz/dot/wf for neighbor p at factor k.

constexpr int T = 3;
constexpr int N = 50000;
constexpr int D = 64;
constexpr int M = 16;
constexpr float EPS2 = 1e-24f;  // (1e-12)^2

template <int CTRL>
__device__ __forceinline__ float dpp_add(float v) {
    // mov_dpp with undef old -> GCNDPPCombine fuses into v_add_f32_dpp
    int rot = __builtin_amdgcn_mov_dpp(__float_as_int(v), CTRL, 0xF, 0xF, false);
    return v + __int_as_float(rot);
}
// sum over the 16 lanes of a DPP row; result broadcast within the row
__device__ __forceinline__ float rowsum16(float v) {
    v = dpp_add<0x128>(v);  // row_ror:8
    v = dpp_add<0x124>(v);  // row_ror:4
    v = dpp_add<0x122>(v);  // row_ror:2
    v = dpp_add<0x121>(v);  // row_ror:1
    return v;
}

__global__ __launch_bounds__(256, 3) void eaconv_fused(
    const float* __restrict__ x_all,   // [T,N,D]
    const int*   __restrict__ nbr_all, // [T,N,M]
    float*       __restrict__ out)     // [T,N,D]
{
    __shared__ float ub[4][D];         // per-wave u broadcast row (256B)
    __shared__ float wb[4][D];         // per-wave weight broadcast row
    const int wv   = threadIdx.x >> 6;
    const int i    = blockIdx.x * 4 + wv;   // N%4==0
    const int lane = threadIdx.x & 63;
    const int p  = lane & 15;          // neighbor index (row domain)
    const int k  = lane >> 4;          // factor
    float* uw  = ub[wv];
    float* wwp = wb[wv];
    const int rowb = 64 * k;           // byte offset of row k in u/w buffers

    float acc = 0.f;
    const float s1q = 0.25f * 0.7310585786300049f;  // 0.25*sigmoid(1)

    // ---- prologue: issue ALL of t=0's loads ----
    int jc = nbr_all[(size_t)i * M + p];
    bool valid = (unsigned)jc < (unsigned)N;
    jc = valid ? jc : 0;
    float xv = x_all[(size_t)i * D + lane];
    float zr[16];                       // z columns: zr[m] = z[m][lane], RAW
#pragma unroll
    for (int m = 0; m < 16; ++m) {
        const int jm = __builtin_amdgcn_readlane(jc, m);
        zr[m] = x_all[(size_t)jm * D + lane];
    }
    const float* zrp0 = x_all + (size_t)jc * D + 16 * k;
    float4 zw0 = *(const float4*)(zrp0 + 0);
    float4 zw1 = *(const float4*)(zrp0 + 4);
    float4 zw2 = *(const float4*)(zrp0 + 8);
    float4 zw3 = *(const float4*)(zrp0 + 12);

#pragma unroll
    for (int t = 0; t < T; ++t) {
        // ---- prefetch t+1 scalars immediately (longest chains first) ----
        int jn = 0; bool validn = false; float xvn = 0.f;
        const float* xn = x_all + (size_t)(t + 1) * N * D;
        if (t < T - 1) {
            jn = nbr_all[((size_t)(t + 1) * N + i) * M + p];
            validn = (unsigned)jn < (unsigned)N;
            jn = validn ? jn : 0;
            xvn = xn[(size_t)i * D + lane];
        }

        // ---- unpack current zrow (RAW) ----
        float zrow[16] = {zw0.x,zw0.y,zw0.z,zw0.w, zw1.x,zw1.y,zw1.z,zw1.w,
                          zw2.x,zw2.y,zw2.z,zw2.w, zw3.x,zw3.y,zw3.z,zw3.w};

        // ---- own x dim + factor norm (DPP over the 16-lane row) ----
        const float sx = rowsum16(xv * xv);
        const float xh = xv * __builtin_amdgcn_rsqf(fmaxf(sx, EPS2));

        // ---- neighbor factor norm (per-lane serial) ----
        float b0 = zrow[0]*zrow[0], b1 = zrow[1]*zrow[1],
              b2 = zrow[2]*zrow[2], b3 = zrow[3]*zrow[3];
#pragma unroll
        for (int q = 4; q < 16; q += 4) {
            b0 = fmaf(zrow[q+0], zrow[q+0], b0);
            b1 = fmaf(zrow[q+1], zrow[q+1], b1);
            b2 = fmaf(zrow[q+2], zrow[q+2], b2);
            b3 = fmaf(zrow[q+3], zrow[q+3], b3);
        }
        float rz = __builtin_amdgcn_rsqf(fmaxf((b0+b1)+(b2+b3), EPS2));
        if (!valid) rz = 0.f;            // pad row -> contributes nothing

        // ---- iter 0: weight row IS rz; u_dir = 4*xh + sum_m rz_m*zr[m] ----
        wwp[lane] = rz;
        float wfr[16];
        {
            const float4 v0 = *(const float4*)((char*)wwp + rowb);
            const float4 v1 = *(const float4*)((char*)wwp + rowb + 16);
            const float4 v2 = *(const float4*)((char*)wwp + rowb + 32);
            const float4 v3 = *(const float4*)((char*)wwp + rowb + 48);
            wfr[ 0]=v0.x; wfr[ 1]=v0.y; wfr[ 2]=v0.z; wfr[ 3]=v0.w;
            wfr[ 4]=v1.x; wfr[ 5]=v1.y; wfr[ 6]=v1.z; wfr[ 7]=v1.w;
            wfr[ 8]=v2.x; wfr[ 9]=v2.y; wfr[10]=v2.z; wfr[11]=v2.w;
            wfr[12]=v3.x; wfr[13]=v3.y; wfr[14]=v3.z; wfr[15]=v3.w;
        }
        float s0 = wfr[0]*zr[0], s1 = wfr[1]*zr[1],
              s2 = wfr[2]*zr[2], s3 = wfr[3]*zr[3];
#pragma unroll
        for (int q = 4; q < 16; q += 4) {
            s0 = fmaf(wfr[q+0], zr[q+0], s0);
            s1 = fmaf(wfr[q+1], zr[q+1], s1);
            s2 = fmaf(wfr[q+2], zr[q+2], s2);
            s3 = fmaf(wfr[q+3], zr[q+3], s3);
        }
        float u = fmaf(xh, 4.0f, (s0+s1)+(s2+s3));
        float inv = __builtin_amdgcn_rsqf(fmaxf(rowsum16(u * u), EPS2));
        uw[lane] = u;

        // ---- issue t+1 z gather NOW: hides under iters 1-2 compute ----
        float zrn[16]; float4 zn0, zn1, zn2, zn3;
        if (t < T - 1) {
#pragma unroll
            for (int m = 0; m < 16; ++m) {
                const int jm = __builtin_amdgcn_readlane(jn, m);
                zrn[m] = xn[(size_t)jm * D + lane];
            }
            const float* zrpn = xn + (size_t)jn * D + 16 * k;
            zn0 = *(const float4*)(zrpn + 0);
            zn1 = *(const float4*)(zrpn + 4);
            zn2 = *(const float4*)(zrpn + 8);
            zn3 = *(const float4*)(zrpn + 12);
        }

        // ---- iters 1..2 ----
#pragma unroll
        for (int it = 1; it < 3; ++it) {
            float urow[16];
            {
                const float4 v0 = *(const float4*)((char*)uw + rowb);
                const float4 v1 = *(const float4*)((char*)uw + rowb + 16);
                const float4 v2 = *(const float4*)((char*)uw + rowb + 32);
                const float4 v3 = *(const float4*)((char*)uw + rowb + 48);
                urow[ 0]=v0.x; urow[ 1]=v0.y; urow[ 2]=v0.z; urow[ 3]=v0.w;
                urow[ 4]=v1.x; urow[ 5]=v1.y; urow[ 6]=v1.z; urow[ 7]=v1.w;
                urow[ 8]=v2.x; urow[ 9]=v2.y; urow[10]=v2.z; urow[11]=v2.w;
                urow[12]=v3.x; urow[13]=v3.y; urow[14]=v3.z; urow[15]=v3.w;
            }
            float d0 = zrow[0]*urow[0], d1 = zrow[1]*urow[1],
                  d2 = zrow[2]*urow[2], d3 = zrow[3]*urow[3];
#pragma unroll
            for (int q = 4; q < 16; q += 4) {
                d0 = fmaf(zrow[q+0], urow[q+0], d0);
                d1 = fmaf(zrow[q+1], urow[q+1], d1);
                d2 = fmaf(zrow[q+2], urow[q+2], d2);
                d3 = fmaf(zrow[q+3], urow[q+3], d3);
            }
            const float logit = ((d0+d1)+(d2+d3)) * (rz * inv);  // zhat.uhat
            const float e = __expf(logit);
            float es = e + __shfl_xor(e, 16, 64);         // softmax over k
            es += __shfl_xor(es, 32, 64);
            const float wf = e * __builtin_amdgcn_rcpf(es) * rz;  // fold rz

            wwp[lane] = wf;
            {
                const float4 v0 = *(const float4*)((char*)wwp + rowb);
                const float4 v1 = *(const float4*)((char*)wwp + rowb + 16);
                const float4 v2 = *(const float4*)((char*)wwp + rowb + 32);
                const float4 v3 = *(const float4*)((char*)wwp + rowb + 48);
                wfr[ 0]=v0.x; wfr[ 1]=v0.y; wfr[ 2]=v0.z; wfr[ 3]=v0.w;
                wfr[ 4]=v1.x; wfr[ 5]=v1.y; wfr[ 6]=v1.z; wfr[ 7]=v1.w;
                wfr[ 8]=v2.x; wfr[ 9]=v2.y; wfr[10]=v2.z; wfr[11]=v2.w;
                wfr[12]=v3.x; wfr[13]=v3.y; wfr[14]=v3.z; wfr[15]=v3.w;
            }
            u = xh;
#pragma unroll
            for (int m = 0; m < 16; ++m) u = fmaf(wfr[m], zr[m], u);
            if (it < 2) {
                inv = __builtin_amdgcn_rsqf(fmaxf(rowsum16(u * u), EPS2));
                uw[lane] = u;
            }
        }

        // ---- temporal blend (scalar) + coalesced store ----
        float wout;
        if (t == 0)      { wout = u; acc = u; }
        else if (t == 1) { wout = 0.25f * acc + 0.5f * u;
                           acc = fmaf(s1q, wout, 0.125f * acc); }
        else             { wout = acc + 0.5f * u; }
        out[((size_t)t * N + i) * D + lane] = wout;

        // ---- rotate pipeline state (free: loop is fully unrolled) ----
        if (t < T - 1) {
            jc = jn; valid = validn; xv = xvn;
#pragma unroll
            for (int m = 0; m < 16; ++m) zr[m] = zrn[m];
            zw0 = zn0; zw1 = zn1; zw2 = zn2; zw3 = zn3;
        }
    }
}

extern "C" void kernel_launch(void* const* d_in, const int* in_sizes, int n_in,
                              void* d_out, int out_size, void* d_ws, size_t ws_size,
                              hipStream_t stream) {
    const float* x_all = (const float*)d_in[0];
    const int*   nbrs  = (const int*)d_in[1];
    float*       out   = (float*)d_out;

    // one wave per node, 4 waves per block, N%4==0
    eaconv_fused<<<N / 4, 256, 0, stream>>>(x_all, nbrs, out);
}

// Round 10
// 182.731 us; speedup vs baseline: 1.2949x; 1.0110x over previous
//
#include <hip/hip_runtime.h>

// EAConv: EM-routing neighbor aggregation + temporal blend, fully fused.
// T=3, b=1, n=50000, d=64, m=16, K=4, dd=16.
// R16: TWO NODES PER WAVE (ILP latency hiding).
// Evidence: R11/R14/R15 all land 114-120us with no pipe >52% busy and
// wall ~= 2x VALU-busy -> latency-bound; compiler refuses cross-t
// prefetch (R15: VGPR stayed 64). Fix: each wave processes nodes A,B =
// 2*waveid, 2*waveid+1. Every phase is duplicated on independent data;
// the scheduler interleaves the two chains, so B's VALU covers A's
// vmcnt/lgkmcnt stalls. TLP halves (R8: occupancy-insensitive), ILP 2x.
// Discriminator: if dur stays ~115, the limiter is random-gather BW
// (292MB @ 2.5TB/s beyond-L2) -> that's the roofline.
// Structure per node = R14/R15 (best verified): zr column gather via
// readlane-SGPR coalesced 256B loads, zrow per-lane row slice, raw-z
// with rz folded into weights, u/w broadcasts via wave-private LDS.
// Lane = d = 16k+p dual-domain. __launch_bounds__(256,3): ~170-reg
// budget for 2x state (R10: no spill at this bound).

constexpr int T = 3;
constexpr int N = 50000;
constexpr int D = 64;
constexpr int M = 16;
constexpr float EPS2 = 1e-24f;  // (1e-12)^2

template <int CTRL>
__device__ __forceinline__ float dpp_add(float v) {
    // mov_dpp with undef old -> GCNDPPCombine fuses into v_add_f32_dpp
    int rot = __builtin_amdgcn_mov_dpp(__float_as_int(v), CTRL, 0xF, 0xF, false);
    return v + __int_as_float(rot);
}
// sum over the 16 lanes of a DPP row; result broadcast within the row
__device__ __forceinline__ float rowsum16(float v) {
    v = dpp_add<0x128>(v);  // row_ror:8
    v = dpp_add<0x124>(v);  // row_ror:4
    v = dpp_add<0x122>(v);  // row_ror:2
    v = dpp_add<0x121>(v);  // row_ror:1
    return v;
}

__global__ __launch_bounds__(256, 3) void eaconv_fused(
    const float* __restrict__ x_all,   // [T,N,D]
    const int*   __restrict__ nbr_all, // [T,N,M]
    float*       __restrict__ out)     // [T,N,D]
{
    __shared__ float ub[4][2][D];      // per-wave, per-node u broadcast row
    __shared__ float wb[4][2][D];      // per-wave, per-node weight row
    const int wv    = threadIdx.x >> 6;
    const int ibase = blockIdx.x * 8 + wv * 2;   // nodes A=ibase, B=ibase+1
    const int lane  = threadIdx.x & 63;
    const int p  = lane & 15;          // neighbor index (row domain)
    const int k  = lane >> 4;          // factor
    const int rowb = 64 * k;           // byte offset of row k in u/w buffers

    float acc[2] = {0.f, 0.f};
    const float s1q = 0.25f * 0.7310585786300049f;  // 0.25*sigmoid(1)

#pragma unroll
    for (int t = 0; t < T; ++t) {
        const float* x = x_all + (size_t)t * N * D;

        int   j[2];  bool vld[2];
        float zr[2][16], zrow[2][16], xh[2], u[2], inv[2], rz[2];

        // ---- neighbor indices (both nodes first: loads issue together) ----
#pragma unroll
        for (int nn = 0; nn < 2; ++nn) {
            const int jj = nbr_all[((size_t)t * N + (ibase + nn)) * M + p];
            vld[nn] = (unsigned)jj < (unsigned)N;
            j[nn] = vld[nn] ? jj : 0;
        }

        // ---- zr column gathers: j_m -> SGPR, coalesced 256B row reads ----
#pragma unroll
        for (int nn = 0; nn < 2; ++nn) {
#pragma unroll
            for (int m = 0; m < 16; ++m) {
                const int jm = __builtin_amdgcn_readlane(j[nn], m);
                zr[nn][m] = x[(size_t)jm * D + lane];
            }
        }

        // ---- zrow row slices (L1-hot: same lines as zr pulls) ----
#pragma unroll
        for (int nn = 0; nn < 2; ++nn) {
            const float* zrp = x + (size_t)j[nn] * D + 16 * k;
            const float4 r0 = *(const float4*)(zrp + 0);
            const float4 r1 = *(const float4*)(zrp + 4);
            const float4 r2 = *(const float4*)(zrp + 8);
            const float4 r3 = *(const float4*)(zrp + 12);
            zrow[nn][ 0]=r0.x; zrow[nn][ 1]=r0.y; zrow[nn][ 2]=r0.z; zrow[nn][ 3]=r0.w;
            zrow[nn][ 4]=r1.x; zrow[nn][ 5]=r1.y; zrow[nn][ 6]=r1.z; zrow[nn][ 7]=r1.w;
            zrow[nn][ 8]=r2.x; zrow[nn][ 9]=r2.y; zrow[nn][10]=r2.z; zrow[nn][11]=r2.w;
            zrow[nn][12]=r3.x; zrow[nn][13]=r3.y; zrow[nn][14]=r3.z; zrow[nn][15]=r3.w;
        }

        // ---- own x dim + factor norm (DPP over the 16-lane row) ----
#pragma unroll
        for (int nn = 0; nn < 2; ++nn) {
            const float xv = x[(size_t)(ibase + nn) * D + lane];
            const float sx = rowsum16(xv * xv);
            xh[nn] = xv * __builtin_amdgcn_rsqf(fmaxf(sx, EPS2));
        }

        // ---- neighbor factor norms (per-lane serial) ----
#pragma unroll
        for (int nn = 0; nn < 2; ++nn) {
            float b0 = zrow[nn][0]*zrow[nn][0], b1 = zrow[nn][1]*zrow[nn][1],
                  b2 = zrow[nn][2]*zrow[nn][2], b3 = zrow[nn][3]*zrow[nn][3];
#pragma unroll
            for (int q = 4; q < 16; q += 4) {
                b0 = fmaf(zrow[nn][q+0], zrow[nn][q+0], b0);
                b1 = fmaf(zrow[nn][q+1], zrow[nn][q+1], b1);
                b2 = fmaf(zrow[nn][q+2], zrow[nn][q+2], b2);
                b3 = fmaf(zrow[nn][q+3], zrow[nn][q+3], b3);
            }
            rz[nn] = __builtin_amdgcn_rsqf(fmaxf((b0+b1)+(b2+b3), EPS2));
            if (!vld[nn]) rz[nn] = 0.f;   // pad row contributes nothing
        }

        // ---- iter 0: weight row IS rz; u = 4*xh + sum_m rz_m*zr[m] ----
#pragma unroll
        for (int nn = 0; nn < 2; ++nn) wb[wv][nn][lane] = rz[nn];
#pragma unroll
        for (int nn = 0; nn < 2; ++nn) {
            float wfr[16];
            const char* wbase = (const char*)wb[wv][nn] + rowb;
            {
                const float4 v0 = *(const float4*)(wbase);
                const float4 v1 = *(const float4*)(wbase + 16);
                const float4 v2 = *(const float4*)(wbase + 32);
                const float4 v3 = *(const float4*)(wbase + 48);
                wfr[ 0]=v0.x; wfr[ 1]=v0.y; wfr[ 2]=v0.z; wfr[ 3]=v0.w;
                wfr[ 4]=v1.x; wfr[ 5]=v1.y; wfr[ 6]=v1.z; wfr[ 7]=v1.w;
                wfr[ 8]=v2.x; wfr[ 9]=v2.y; wfr[10]=v2.z; wfr[11]=v2.w;
                wfr[12]=v3.x; wfr[13]=v3.y; wfr[14]=v3.z; wfr[15]=v3.w;
            }
            float s0 = wfr[0]*zr[nn][0], s1 = wfr[1]*zr[nn][1],
                  s2 = wfr[2]*zr[nn][2], s3 = wfr[3]*zr[nn][3];
#pragma unroll
            for (int q = 4; q < 16; q += 4) {
                s0 = fmaf(wfr[q+0], zr[nn][q+0], s0);
                s1 = fmaf(wfr[q+1], zr[nn][q+1], s1);
                s2 = fmaf(wfr[q+2], zr[nn][q+2], s2);
                s3 = fmaf(wfr[q+3], zr[nn][q+3], s3);
            }
            u[nn] = fmaf(xh[nn], 4.0f, (s0+s1)+(s2+s3));
            inv[nn] = __builtin_amdgcn_rsqf(fmaxf(rowsum16(u[nn]*u[nn]), EPS2));
            ub[wv][nn][lane] = u[nn];
        }

        // ---- iters 1..2 ----
#pragma unroll
        for (int it = 1; it < 3; ++it) {
            float wfv[2];
#pragma unroll
            for (int nn = 0; nn < 2; ++nn) {
                float urow[16];
                const char* ubase = (const char*)ub[wv][nn] + rowb;
                {
                    const float4 v0 = *(const float4*)(ubase);
                    const float4 v1 = *(const float4*)(ubase + 16);
                    const float4 v2 = *(const float4*)(ubase + 32);
                    const float4 v3 = *(const float4*)(ubase + 48);
                    urow[ 0]=v0.x; urow[ 1]=v0.y; urow[ 2]=v0.z; urow[ 3]=v0.w;
                    urow[ 4]=v1.x; urow[ 5]=v1.y; urow[ 6]=v1.z; urow[ 7]=v1.w;
                    urow[ 8]=v2.x; urow[ 9]=v2.y; urow[10]=v2.z; urow[11]=v2.w;
                    urow[12]=v3.x; urow[13]=v3.y; urow[14]=v3.z; urow[15]=v3.w;
                }
                float d0 = zrow[nn][0]*urow[0], d1 = zrow[nn][1]*urow[1],
                      d2 = zrow[nn][2]*urow[2], d3 = zrow[nn][3]*urow[3];
#pragma unroll
                for (int q = 4; q < 16; q += 4) {
                    d0 = fmaf(zrow[nn][q+0], urow[q+0], d0);
                    d1 = fmaf(zrow[nn][q+1], urow[q+1], d1);
                    d2 = fmaf(zrow[nn][q+2], urow[q+2], d2);
                    d3 = fmaf(zrow[nn][q+3], urow[q+3], d3);
                }
                const float logit = ((d0+d1)+(d2+d3)) * (rz[nn] * inv[nn]);
                const float e = __expf(logit);
                float es = e + __shfl_xor(e, 16, 64);   // softmax over k
                es += __shfl_xor(es, 32, 64);
                wfv[nn] = e * __builtin_amdgcn_rcpf(es) * rz[nn];  // fold rz
            }
#pragma unroll
            for (int nn = 0; nn < 2; ++nn) wb[wv][nn][lane] = wfv[nn];
#pragma unroll
            for (int nn = 0; nn < 2; ++nn) {
                float wfr[16];
                const char* wbase = (const char*)wb[wv][nn] + rowb;
                {
                    const float4 v0 = *(const float4*)(wbase);
                    const float4 v1 = *(const float4*)(wbase + 16);
                    const float4 v2 = *(const float4*)(wbase + 32);
                    const float4 v3 = *(const float4*)(wbase + 48);
                    wfr[ 0]=v0.x; wfr[ 1]=v0.y; wfr[ 2]=v0.z; wfr[ 3]=v0.w;
                    wfr[ 4]=v1.x; wfr[ 5]=v1.y; wfr[ 6]=v1.z; wfr[ 7]=v1.w;
                    wfr[ 8]=v2.x; wfr[ 9]=v2.y; wfr[10]=v2.z; wfr[11]=v2.w;
                    wfr[12]=v3.x; wfr[13]=v3.y; wfr[14]=v3.z; wfr[15]=v3.w;
                }
                float uu = xh[nn];
#pragma unroll
                for (int m = 0; m < 16; ++m) uu = fmaf(wfr[m], zr[nn][m], uu);
                u[nn] = uu;
                if (it < 2) {
                    inv[nn] = __builtin_amdgcn_rsqf(
                        fmaxf(rowsum16(uu * uu), EPS2));
                    ub[wv][nn][lane] = uu;
                }
            }
        }

        // ---- temporal blend (scalar) + coalesced store ----
#pragma unroll
        for (int nn = 0; nn < 2; ++nn) {
            float wout;
            if (t == 0)      { wout = u[nn]; acc[nn] = u[nn]; }
            else if (t == 1) { wout = 0.25f * acc[nn] + 0.5f * u[nn];
                               acc[nn] = fmaf(s1q, wout, 0.125f * acc[nn]); }
            else             { wout = acc[nn] + 0.5f * u[nn]; }
            out[((size_t)t * N + (ibase + nn)) * D + lane] = wout;
        }
    }
}

extern "C" void kernel_launch(void* const* d_in, const int* in_sizes, int n_in,
                              void* d_out, int out_size, void* d_ws, size_t ws_size,
                              hipStream_t stream) {
    const float* x_all = (const float*)d_in[0];
    const int*   nbrs  = (const int*)d_in[1];
    float*       out   = (float*)d_out;

    // two nodes per wave, 4 waves per block -> 8 nodes/block; N%8==0
    eaconv_fused<<<N / 8, 256, 0, stream>>>(x_all, nbrs, out);
}

// Round 11
// 176.178 us; speedup vs baseline: 1.3430x; 1.0372x over previous
//
#include <hip/hip_runtime.h>

// EAConv: EM-routing neighbor aggregation + temporal blend, fully fused.
// T=3, b=1, n=50000, d=64, m=16, K=4, dd=16.
// R17 = R15 structure + SCHED_BARRIER-PINNED cross-t prefetch.
// Evidence: R11/R14/R15/R16 plateau 114-128us, no pipe >52%, FETCH at the
// 292MB L2-miss floor, HBM 2.6/6.3 TB/s -> latency-bound. R15/R16 failed
// because the scheduler SANK prefetch loads to first use (VGPR pinned 64).
// Fix: per t, issue t+1's 22 loads right after iter0, then
// __builtin_amdgcn_sched_barrier(0): no instruction may cross, so the
// loads provably issue before iters 1-2 (~1200cy) and complete during
// them. Static double-buffer zrA/zrB (no rotation copies = no sink
// target; all indexing compile-time per rule #20).
// __launch_bounds__(256,2): 256-reg ceiling for the ~105-reg live window.
// Per-node structure = R14/R15 (verified): zr column gather via
// readlane-SGPR coalesced 256B loads, zrow per-lane row slice (L1-hot),
// raw-z with rz folded into weights, u/w broadcast via wave-private LDS,
// softmax over k via shfl_xor, norms via 16-lane DPP rowsum.
// Lane = d = 16k+p dual-domain.

constexpr int T = 3;
constexpr int N = 50000;
constexpr int D = 64;
constexpr int M = 16;
constexpr float EPS2 = 1e-24f;  // (1e-12)^2

template <int CTRL>
__device__ __forceinline__ float dpp_add(float v) {
    // mov_dpp with undef old -> GCNDPPCombine fuses into v_add_f32_dpp
    int rot = __builtin_amdgcn_mov_dpp(__float_as_int(v), CTRL, 0xF, 0xF, false);
    return v + __int_as_float(rot);
}
// sum over the 16 lanes of a DPP row; result broadcast within the row
__device__ __forceinline__ float rowsum16(float v) {
    v = dpp_add<0x128>(v);  // row_ror:8
    v = dpp_add<0x124>(v);  // row_ror:4
    v = dpp_add<0x122>(v);  // row_ror:2
    v = dpp_add<0x121>(v);  // row_ror:1
    return v;
}

__global__ __launch_bounds__(256, 2) void eaconv_fused(
    const float* __restrict__ x_all,   // [T,N,D]
    const int*   __restrict__ nbr_all, // [T,N,M]
    float*       __restrict__ out)     // [T,N,D]
{
    __shared__ float ub[4][D];         // per-wave u broadcast row (256B)
    __shared__ float wb[4][D];         // per-wave weight broadcast row
    const int wv   = threadIdx.x >> 6;
    const int i    = blockIdx.x * 4 + wv;   // N%4==0
    const int lane = threadIdx.x & 63;
    const int p = lane & 15;           // neighbor index (row domain)
    const int k = lane >> 4;           // factor
    float* uw  = ub[wv];
    float* wwp = wb[wv];
    const int rowb = 64 * k;           // byte offset of row k in u/w buffers

    const float s1q = 0.25f * 0.7310585786300049f;  // 0.25*sigmoid(1)

    // ---- z block loader: zr columns (coalesced via readlane-SGPR) +
    //      zrow row slice (per-lane, L1-hot from the same lines) ----
    auto load_z = [&](const float* xs, int j,
                      float (&zr)[16], float (&zrow)[16]) {
#pragma unroll
        for (int m = 0; m < 16; ++m) {
            const int jm = __builtin_amdgcn_readlane(j, m);
            zr[m] = xs[(size_t)jm * D + lane];
        }
        const float* zrp = xs + (size_t)j * D + 16 * k;
        const float4 r0 = *(const float4*)(zrp + 0);
        const float4 r1 = *(const float4*)(zrp + 4);
        const float4 r2 = *(const float4*)(zrp + 8);
        const float4 r3 = *(const float4*)(zrp + 12);
        zrow[ 0]=r0.x; zrow[ 1]=r0.y; zrow[ 2]=r0.z; zrow[ 3]=r0.w;
        zrow[ 4]=r1.x; zrow[ 5]=r1.y; zrow[ 6]=r1.z; zrow[ 7]=r1.w;
        zrow[ 8]=r2.x; zrow[ 9]=r2.y; zrow[10]=r2.z; zrow[11]=r2.w;
        zrow[12]=r3.x; zrow[13]=r3.y; zrow[14]=r3.z; zrow[15]=r3.w;
    };

    // ---- one EM solve; `prefetch` issued after iter0, then pinned ----
    auto em = [&](const float (&zr)[16], const float (&zrow)[16],
                  float xv, bool valid, auto&& prefetch) -> float {
        // own factor norm (DPP over the 16-lane row)
        const float sx = rowsum16(xv * xv);
        const float xh = xv * __builtin_amdgcn_rsqf(fmaxf(sx, EPS2));
        // neighbor factor norm (per-lane serial)
        float b0 = zrow[0]*zrow[0], b1 = zrow[1]*zrow[1],
              b2 = zrow[2]*zrow[2], b3 = zrow[3]*zrow[3];
#pragma unroll
        for (int q = 4; q < 16; q += 4) {
            b0 = fmaf(zrow[q+0], zrow[q+0], b0);
            b1 = fmaf(zrow[q+1], zrow[q+1], b1);
            b2 = fmaf(zrow[q+2], zrow[q+2], b2);
            b3 = fmaf(zrow[q+3], zrow[q+3], b3);
        }
        float rz = __builtin_amdgcn_rsqf(fmaxf((b0+b1)+(b2+b3), EPS2));
        if (!valid) rz = 0.f;            // pad row contributes nothing

        // iter 0: weight row IS rz; u = 4*xh + sum_m rz_m*zr[m]
        wwp[lane] = rz;
        float wfr[16];
        {
            const float4 v0 = *(const float4*)((char*)wwp + rowb);
            const float4 v1 = *(const float4*)((char*)wwp + rowb + 16);
            const float4 v2 = *(const float4*)((char*)wwp + rowb + 32);
            const float4 v3 = *(const float4*)((char*)wwp + rowb + 48);
            wfr[ 0]=v0.x; wfr[ 1]=v0.y; wfr[ 2]=v0.z; wfr[ 3]=v0.w;
            wfr[ 4]=v1.x; wfr[ 5]=v1.y; wfr[ 6]=v1.z; wfr[ 7]=v1.w;
            wfr[ 8]=v2.x; wfr[ 9]=v2.y; wfr[10]=v2.z; wfr[11]=v2.w;
            wfr[12]=v3.x; wfr[13]=v3.y; wfr[14]=v3.z; wfr[15]=v3.w;
        }
        float s0 = wfr[0]*zr[0], s1 = wfr[1]*zr[1],
              s2 = wfr[2]*zr[2], s3 = wfr[3]*zr[3];
#pragma unroll
        for (int q = 4; q < 16; q += 4) {
            s0 = fmaf(wfr[q+0], zr[q+0], s0);
            s1 = fmaf(wfr[q+1], zr[q+1], s1);
            s2 = fmaf(wfr[q+2], zr[q+2], s2);
            s3 = fmaf(wfr[q+3], zr[q+3], s3);
        }
        float u = fmaf(xh, 4.0f, (s0+s1)+(s2+s3));
        float inv = __builtin_amdgcn_rsqf(fmaxf(rowsum16(u * u), EPS2));
        uw[lane] = u;

        // ---- issue next-t loads HERE; barrier forbids sinking them ----
        prefetch();
        __builtin_amdgcn_sched_barrier(0);

        // iters 1..2
#pragma unroll
        for (int it = 1; it < 3; ++it) {
            float urow[16];
            {
                const float4 v0 = *(const float4*)((char*)uw + rowb);
                const float4 v1 = *(const float4*)((char*)uw + rowb + 16);
                const float4 v2 = *(const float4*)((char*)uw + rowb + 32);
                const float4 v3 = *(const float4*)((char*)uw + rowb + 48);
                urow[ 0]=v0.x; urow[ 1]=v0.y; urow[ 2]=v0.z; urow[ 3]=v0.w;
                urow[ 4]=v1.x; urow[ 5]=v1.y; urow[ 6]=v1.z; urow[ 7]=v1.w;
                urow[ 8]=v2.x; urow[ 9]=v2.y; urow[10]=v2.z; urow[11]=v2.w;
                urow[12]=v3.x; urow[13]=v3.y; urow[14]=v3.z; urow[15]=v3.w;
            }
            float d0 = zrow[0]*urow[0], d1 = zrow[1]*urow[1],
                  d2 = zrow[2]*urow[2], d3 = zrow[3]*urow[3];
#pragma unroll
            for (int q = 4; q < 16; q += 4) {
                d0 = fmaf(zrow[q+0], urow[q+0], d0);
                d1 = fmaf(zrow[q+1], urow[q+1], d1);
                d2 = fmaf(zrow[q+2], urow[q+2], d2);
                d3 = fmaf(zrow[q+3], urow[q+3], d3);
            }
            const float logit = ((d0+d1)+(d2+d3)) * (rz * inv);  // zhat.uhat
            const float e = __expf(logit);
            float es = e + __shfl_xor(e, 16, 64);   // softmax over k
            es += __shfl_xor(es, 32, 64);
            const float wf = e * __builtin_amdgcn_rcpf(es) * rz;  // fold rz

            wwp[lane] = wf;
            {
                const float4 v0 = *(const float4*)((char*)wwp + rowb);
                const float4 v1 = *(const float4*)((char*)wwp + rowb + 16);
                const float4 v2 = *(const float4*)((char*)wwp + rowb + 32);
                const float4 v3 = *(const float4*)((char*)wwp + rowb + 48);
                wfr[ 0]=v0.x; wfr[ 1]=v0.y; wfr[ 2]=v0.z; wfr[ 3]=v0.w;
                wfr[ 4]=v1.x; wfr[ 5]=v1.y; wfr[ 6]=v1.z; wfr[ 7]=v1.w;
                wfr[ 8]=v2.x; wfr[ 9]=v2.y; wfr[10]=v2.z; wfr[11]=v2.w;
                wfr[12]=v3.x; wfr[13]=v3.y; wfr[14]=v3.z; wfr[15]=v3.w;
            }
            float uu = xh;
#pragma unroll
            for (int m = 0; m < 16; ++m) uu = fmaf(wfr[m], zr[m], uu);
            u = uu;
            if (it < 2) {
                inv = __builtin_amdgcn_rsqf(fmaxf(rowsum16(u * u), EPS2));
                uw[lane] = u;
            }
        }
        return u;
    };

    // ---- prologue: t=0 full load + t=1 scalars issued together ----
    int j0 = nbr_all[(size_t)i * M + p];
    const bool v0 = (unsigned)j0 < (unsigned)N;
    j0 = v0 ? j0 : 0;
    const float xv0 = x_all[(size_t)i * D + lane];
    float zrA[16], zrowA[16], zrB[16], zrowB[16];
    load_z(x_all, j0, zrA, zrowA);
    const int   jr1 = nbr_all[((size_t)N + i) * M + p];
    const float xv1 = x_all[((size_t)N + i) * D + lane];
    __builtin_amdgcn_sched_barrier(0);

    bool v1 = false, v2 = false;
    int jr2 = 0; float xv2 = 0.f;

    // ---- t = 0 : compute A, prefetch B(t=1) + t=2 scalars ----
    float u = em(zrA, zrowA, xv0, v0, [&] {
        v1 = (unsigned)jr1 < (unsigned)N;
        const int j1 = v1 ? jr1 : 0;
        load_z(x_all + (size_t)N * D, j1, zrB, zrowB);
        jr2 = nbr_all[((size_t)2 * N + i) * M + p];
        xv2 = x_all[((size_t)2 * N + i) * D + lane];
    });
    float acc = u;
    out[(size_t)i * D + lane] = u;

    // ---- t = 1 : compute B, prefetch A(t=2) ----
    u = em(zrB, zrowB, xv1, v1, [&] {
        v2 = (unsigned)jr2 < (unsigned)N;
        const int j2 = v2 ? jr2 : 0;
        load_z(x_all + (size_t)2 * N * D, j2, zrA, zrowA);
    });
    const float e1 = 0.25f * acc + 0.5f * u;
    out[((size_t)N + i) * D + lane] = e1;
    acc = fmaf(s1q, e1, 0.125f * acc);

    // ---- t = 2 : compute A, no prefetch ----
    u = em(zrA, zrowA, xv2, v2, [] {});
    out[((size_t)2 * N + i) * D + lane] = acc + 0.5f * u;
}

extern "C" void kernel_launch(void* const* d_in, const int* in_sizes, int n_in,
                              void* d_out, int out_size, void* d_ws, size_t ws_size,
                              hipStream_t stream) {
    const float* x_all = (const float*)d_in[0];
    const int*   nbrs  = (const int*)d_in[1];
    float*       out   = (float*)d_out;

    // one node per wave, 4 waves per block, N%4==0
    eaconv_fused<<<N / 4, 256, 0, stream>>>(x_all, nbrs, out);
}